// Round 11
// baseline (329.271 us; speedup 1.0000x reference)
//
#include <hip/hip_runtime.h>
#include <hip/hip_bf16.h>

// B=32, K=64, D=256, LS=128, rows = 2048

using bf16 = __hip_bfloat16;
typedef short bf16x8 __attribute__((ext_vector_type(8)));
typedef float f32x4 __attribute__((ext_vector_type(4)));

__device__ __forceinline__ float bfu(unsigned short u) { return __uint_as_float(((unsigned)u) << 16); }

__device__ __forceinline__ unsigned short bfr(float v) {   // RNE fp32->bf16 bits
  unsigned u = __float_as_uint(v);
  u += 0x7FFFu + ((u >> 16) & 1u);
  return (unsigned short)(u >> 16);
}

__device__ __forceinline__ float gelu_e(float x) {
  return 0.5f * x * (1.0f + erff(x * 0.7071067811865475f));
}

__device__ __forceinline__ float load_f(const void* p, int i, int fl) {
  if (fl) return bfu(((const unsigned short*)p)[i]);
  return ((const float*)p)[i];
}

// per-block inline dtype detect: 1 = inputs are bf16
__device__ __forceinline__ int block_detect(const void* X) {
  __shared__ int bad_s;
  if (threadIdx.x == 0) bad_s = 0;
  __syncthreads();
  if (threadIdx.x < 256) {
    const float v = bfu(((const unsigned short*)X)[threadIdx.x]);
    if (!(fabsf(v) < 1e6f)) atomicOr(&bad_s, 1);
  }
  __syncthreads();
  return bad_s ? 0 : 1;
}

// stage one float4 (row, d0) into hi/lo MFMA A-fragments
__device__ __forceinline__ void stage_split4(unsigned short (&aF)[2][4096], int row, int d0, float4 v) {
  ushort4 h, lo;
  h.x = bfr(v.x); h.y = bfr(v.y); h.z = bfr(v.z); h.w = bfr(v.w);
  lo.x = bfr(v.x - bfu(h.x)); lo.y = bfr(v.y - bfu(h.y));
  lo.z = bfr(v.z - bfu(h.z)); lo.w = bfr(v.w - bfu(h.w));
  const int kt = d0 >> 5, lane = row | (((d0 >> 3) & 3) << 4), j = d0 & 7;
  *(ushort4*)&aF[0][kt*512 + lane*8 + j] = h;
  *(ushort4*)&aF[1][kt*512 + lane*8 + j] = lo;
}

// ---------------------------------------------------------------------------
// prep phase (512 thr, 32 KB LDS): weights -> ws. wfb only for layer 1.
// roles: [0,8) A: wfb l=1 (kt) 2 passes | [8,56) B: w3b | [56,80) D: wh
//        80 E: bc + zero counters/ssacc
// ---------------------------------------------------------------------------
__device__ void prep_phase(
    int blk, int t, int fl, char* psm,
    const void* kw, const void* qw, const void* rw1, const void* rw2,
    const void* mw1, const void* mw2, const void* pw, const void* muw, const void* spw,
    const void* rb1, const void* rb2, const void* lng, const void* lnb,
    const void* mb1, const void* mb2, const void* pb, const void* mub, const void* spb,
    unsigned short* wfb, unsigned short* w3b, float* wh, float* bc,
    unsigned* cnts, float* ssacc)
{
  if (blk < 8) {   // ---- A: wfb (l=1, kt), 2 passes of 32 KB; q UNSCALED
    unsigned short* ls = (unsigned short*)psm;
    unsigned* lsu = (unsigned*)psm;
    const int l = 1, kt = blk;
    #pragma unroll
    for (int pass = 0; pass < 2; ++pass) {
      if (pass == 0) {        // kw | qw
        if (fl) {
          #pragma unroll
          for (int s = 0; s < 2; ++s) {
            const unsigned* sp = (const unsigned*)((s == 0) ? kw : qw);
            for (int i = t; i < 4096; i += 512) {
              const int e = i >> 4, d2 = i & 15;
              lsu[s*4096 + i] = sp[(l*256 + e)*128 + kt*16 + d2];
            }
          }
        } else {
          #pragma unroll
          for (int s = 0; s < 2; ++s) {
            const float* sp = (const float*)((s == 0) ? kw : qw);
            for (int i = t; i < 4096; i += 512) {
              const int e = i >> 4, d2 = i & 15;
              const float f0 = sp[(l*256 + e)*256 + kt*32 + d2*2];
              const float f1 = sp[(l*256 + e)*256 + kt*32 + d2*2 + 1];
              lsu[s*4096 + i] = (unsigned)bfr(f0) | ((unsigned)bfr(f1) << 16);
            }
          }
        }
      } else {                // rw1: Wa | Wb
        if (fl) {
          const unsigned* sp = (const unsigned*)rw1;
          #pragma unroll
          for (int s = 0; s < 2; ++s)
            for (int i = t; i < 4096; i += 512) {
              const int e = i >> 4, d2 = i & 15;
              lsu[s*4096 + i] = sp[(l*256 + e)*256 + s*128 + kt*16 + d2];
            }
        } else {
          const float* sp = (const float*)rw1;
          #pragma unroll
          for (int s = 0; s < 2; ++s)
            for (int i = t; i < 4096; i += 512) {
              const int e = i >> 4, d2 = i & 15;
              const float f0 = sp[(l*256 + e)*512 + s*256 + kt*32 + d2*2];
              const float f1 = sp[(l*256 + e)*512 + s*256 + kt*32 + d2*2 + 1];
              lsu[s*4096 + i] = (unsigned)bfr(f0) | ((unsigned)bfr(f1) << 16);
            }
        }
      }
      __syncthreads();
      unsigned* outp = (unsigned*)wfb + (8 + kt)*16384 + pass*8192;   // l=1 region
      for (int f2 = t; f2 < 8192; f2 += 512) {
        const int j2 = f2 & 3, lane = (f2 >> 2) & 63, ntl = f2 >> 8;
        const int seg = ntl >> 4;
        const int e = (ntl & 15)*16 + (lane & 15);
        const int dl = ((lane >> 4) & 3)*8 + j2*2;
        unsigned short r0 = ls[seg*8192 + e*32 + dl];
        unsigned short r1 = ls[seg*8192 + e*32 + dl + 1];
        if (pass == 1 && seg == 0) {   // Wa+Wb
          const unsigned short w0 = ls[8192 + e*32 + dl];
          const unsigned short w1 = ls[8192 + e*32 + dl + 1];
          r0 = bfr(bfu(r0) + bfu(w0)); r1 = bfr(bfu(r1) + bfu(w1));
        }
        outp[f2] = (unsigned)r0 | ((unsigned)r1 << 16);
      }
      __syncthreads();
    }
    return;
  }
  int b2 = blk - 8;
  if (b2 < 48) {   // ---- B: w3b (l,gm,kt)
    unsigned short* ls = (unsigned short*)psm;
    unsigned* lsu = (unsigned*)psm;
    const int l3 = b2 >> 3, kt = b2 & 7;
    const int l = l3 / 3, gm = l3 % 3;
    const void* src = (gm == 0) ? rw2 : (gm == 1) ? mw1 : mw2;
    if (fl) {
      const unsigned* sp = (const unsigned*)src;
      for (int i = t; i < 4096; i += 512) {
        const int e = i >> 4, d2 = i & 15;
        lsu[i] = sp[(l*256 + e)*128 + kt*16 + d2];
      }
    } else {
      const float* sp = (const float*)src;
      for (int i = t; i < 4096; i += 512) {
        const int e = i >> 4, d2 = i & 15;
        const float f0 = sp[(l*256 + e)*256 + kt*32 + d2*2];
        const float f1 = sp[(l*256 + e)*256 + kt*32 + d2*2 + 1];
        lsu[i] = (unsigned)bfr(f0) | ((unsigned)bfr(f1) << 16);
      }
    }
    __syncthreads();
    unsigned* outp = (unsigned*)w3b + (l3*8 + kt)*4096;
    for (int f2 = t; f2 < 4096; f2 += 512) {
      const int j2 = f2 & 3, lane = (f2 >> 2) & 63, nt = f2 >> 8;
      const int e = nt*16 + (lane & 15);
      const int dl = ((lane >> 4) & 3)*8 + j2*2;
      outp[f2] = (unsigned)ls[e*32 + dl] | ((unsigned)ls[e*32 + dl + 1] << 16);
    }
    return;
  }
  b2 -= 48;
  if (b2 < 24) {   // ---- D: wh transposes
    float* lsf = (float*)psm;
    if (b2 < 8) {          // projT
      const int l0 = b2*16;
      if (fl) {
        const unsigned* sp = (const unsigned*)pw;
        for (int i = t; i < 2048; i += 512) {
          const int ll = i >> 7, d2 = i & 127;
          const unsigned u = sp[(l0 + ll)*128 + d2];
          lsf[ll*256 + d2*2]     = __uint_as_float(u << 16);
          lsf[ll*256 + d2*2 + 1] = __uint_as_float(u & 0xffff0000u);
        }
      } else {
        const float* sp = (const float*)pw;
        for (int i = t; i < 4096; i += 512) {
          const int ll = i >> 8, d = i & 255;
          lsf[ll*256 + d] = sp[(l0 + ll)*256 + d];
        }
      }
      __syncthreads();
      for (int i = t; i < 4096; i += 512) {
        const int d = i >> 4, ll = i & 15;
        wh[d*128 + l0 + ll] = lsf[ll*256 + d];
      }
    } else {                // muT / spT
      const int grp2 = b2 - 8;
      const int isSp = grp2 >> 3;
      const int l0 = (grp2 & 7)*16;
      const void* src = isSp ? spw : muw;
      const int off = isSp ? 49152 : 32768;
      if (fl) {
        const unsigned* sp = (const unsigned*)src;
        for (int i = t; i < 1024; i += 512) {
          const int ll = i >> 6, c2 = i & 63;
          const unsigned u = sp[(l0 + ll)*64 + c2];
          lsf[ll*128 + c2*2]     = __uint_as_float(u << 16);
          lsf[ll*128 + c2*2 + 1] = __uint_as_float(u & 0xffff0000u);
        }
      } else {
        const float* sp = (const float*)src;
        for (int i = t; i < 2048; i += 512) {
          const int ll = i >> 7, c = i & 127;
          lsf[ll*128 + c] = sp[(l0 + ll)*128 + c];
        }
      }
      __syncthreads();
      for (int i = t; i < 2048; i += 512) {
        const int c = i >> 4, ll = i & 15;
        wh[off + c*128 + l0 + ll] = lsf[ll*128 + c];
      }
    }
    return;
  }
  if (b2 == 24) {  // ---- E: bc + zero counters
    for (int i = t; i < 3456; i += 512) {
      const void* src; int off;
      if (i < 512)       { src = rb1; off = i; }
      else if (i < 1024) { src = rb2; off = i - 512; }
      else if (i < 1536) { src = lng; off = i - 1024; }
      else if (i < 2048) { src = lnb; off = i - 1536; }
      else if (i < 2560) { src = mb1; off = i - 2048; }
      else if (i < 3072) { src = mb2; off = i - 2560; }
      else if (i < 3200) { src = pb;  off = i - 3072; }
      else if (i < 3328) { src = mub; off = i - 3200; }
      else               { src = spb; off = i - 3328; }
      bc[i] = load_f(src, off, fl);
    }
    for (int i = t; i < 288; i += 512) cnts[i] = 0u;       // cntA128|cntB128|cntH32
    for (int i = t; i < 8192; i += 512) ssacc[i] = 0.f;
  }
}

// ---------------------------------------------------------------------------
// raw B-fragment load from row-major layer-0 weights
// ---------------------------------------------------------------------------
__device__ __forceinline__ bf16x8 raw_bfrag(int seg, int e, int d0, int fl,
    const void* kw, const void* qw, const void* rw1)
{
  if (fl) {
    if (seg == 0) return *(const bf16x8*)((const unsigned short*)kw + e*256 + d0);
    if (seg == 1) return *(const bf16x8*)((const unsigned short*)qw + e*256 + d0);
    const unsigned short* r1 = (const unsigned short*)rw1 + e*512;
    const bf16x8 wb = *(const bf16x8*)(r1 + 256 + d0);
    if (seg == 3) return wb;
    const bf16x8 wa = *(const bf16x8*)(r1 + d0);
    bf16x8 r;
    #pragma unroll
    for (int i = 0; i < 8; ++i)
      r[i] = (short)bfr(bfu((unsigned short)wa[i]) + bfu((unsigned short)wb[i]));
    return r;
  } else {
    float vs[8];
    if (seg <= 1) {
      const float* sp = (const float*)((seg == 0) ? kw : qw) + e*256 + d0;
      #pragma unroll
      for (int i = 0; i < 8; ++i) vs[i] = sp[i];
    } else {
      const float* r1 = (const float*)rw1 + e*512;
      #pragma unroll
      for (int i = 0; i < 8; ++i) vs[i] = r1[256 + d0 + i];
      if (seg == 2) {
        #pragma unroll
        for (int i = 0; i < 8; ++i) vs[i] += r1[d0 + i];
      }
    }
    bf16x8 r;
    #pragma unroll
    for (int i = 0; i < 8; ++i) r[i] = (short)bfr(vs[i]);
    return r;
  }
}

// raw k1 body for layer 0: 16 rows x 16 ntg (one segment per block), 512 thr
template<bool SPLIT>
__device__ void k1_raw(const unsigned short (&aF)[2][4096], int seg, int ntg0,
    const void* kw, const void* qw, const void* rw1, const void* rb1, int fl,
    float* __restrict__ kq, float* __restrict__ Pf, unsigned* __restrict__ Qpk,
    int row0, int t)
{
  const int w = t >> 6, l64 = t & 63;
  const int col = l64 & 15, quad = l64 >> 4;
  f32x4 acc[2];
  acc[0] = (f32x4){0.f, 0.f, 0.f, 0.f};
  acc[1] = (f32x4){0.f, 0.f, 0.f, 0.f};
  for (int kt = 0; kt < 8; ++kt) {
    const bf16x8 ah = *(const bf16x8*)&aF[0][kt*512 + l64*8];
    bf16x8 al;
    if (SPLIT) al = *(const bf16x8*)&aF[1][kt*512 + l64*8];
    const int d0 = kt*32 + quad*8;
    #pragma unroll
    for (int i = 0; i < 2; ++i) {
      const int ntg = ntg0 + w*2 + i;
      const int e = (ntg & 15)*16 + col;
      const bf16x8 b = raw_bfrag(seg, e, d0, fl, kw, qw, rw1);
      acc[i] = __builtin_amdgcn_mfma_f32_16x16x32_bf16(ah, b, acc[i], 0, 0, 0);
      if (SPLIT) acc[i] = __builtin_amdgcn_mfma_f32_16x16x32_bf16(al, b, acc[i], 0, 0, 0);
    }
  }
  #pragma unroll
  for (int i = 0; i < 2; ++i) {
    const int ntg = ntg0 + w*2 + i;
    if (seg < 2) {
      const int n = ntg*16 + col;
      #pragma unroll
      for (int r = 0; r < 4; ++r)
        kq[(size_t)(row0 + quad*4 + r)*512 + n] = acc[i][r];
    } else if (seg == 2) {
      const int c = (ntg & 15)*16 + col;
      const float bias = load_f(rb1, c, fl);
      #pragma unroll
      for (int r = 0; r < 4; ++r)
        Pf[(size_t)(row0 + quad*4 + r)*256 + c] = acc[i][r] + bias;
    } else {
      #pragma unroll
      for (int r = 0; r < 4; ++r) {
        const float v = acc[i][r];
        const float pv = __shfl_xor(v, 1, 64);
        if (!(col & 1)) {
          const unsigned uu = (unsigned)bfr(v) | ((unsigned)bfr(pv) << 16);
          Qpk[(size_t)(row0 + quad*4 + r)*128 + (ntg & 15)*8 + (col >> 1)] = uu;
        }
      }
    }
  }
}

// ---------------------------------------------------------------------------
// Kernel A: fused prep (blocks 0..80) + layer-0 k1 from raw weights (81..592)
// ---------------------------------------------------------------------------
__global__ __launch_bounds__(512) void fusedA(
    const void* __restrict__ X, const void* __restrict__ kw, const void* __restrict__ qw,
    const void* __restrict__ rw1, const void* __restrict__ rw2, const void* __restrict__ mw1,
    const void* __restrict__ mw2, const void* __restrict__ pw, const void* __restrict__ muw,
    const void* __restrict__ spw,
    const void* __restrict__ rb1, const void* __restrict__ rb2, const void* __restrict__ lng,
    const void* __restrict__ lnb, const void* __restrict__ mb1, const void* __restrict__ mb2,
    const void* __restrict__ pb, const void* __restrict__ mub, const void* __restrict__ spb,
    unsigned short* __restrict__ wfb, unsigned short* __restrict__ w3b,
    float* __restrict__ wh, float* __restrict__ bc,
    unsigned* __restrict__ cnts, float* __restrict__ ssacc,
    float* __restrict__ kqA, float* __restrict__ PfA, unsigned* __restrict__ QpkA)
{
  __shared__ __align__(16) char smem[32768];
  const int fl = block_detect(X);
  const int t = threadIdx.x;
  const int blk = blockIdx.x;
  if (blk < 81) {
    prep_phase(blk, t, fl, smem, kw, qw, rw1, rw2, mw1, mw2, pw, muw, spw,
               rb1, rb2, lng, lnb, mb1, mb2, pb, mub, spb, wfb, w3b, wh, bc,
               cnts, ssacc);
    return;
  }
  auto& aF = *(unsigned short(*)[2][4096])smem;
  const int rb = blk - 81;
  const int mb = rb >> 2, seg = rb & 3;
  const int row0 = mb * 16, ntg0 = seg * 16;
  if (fl) {
    const int row = t >> 5, d0 = (t & 31) * 8;
    const uint4 u = *(const uint4*)((const unsigned*)X + (size_t)(row0 + row)*128 + (t & 31)*4);
    const int kt = d0 >> 5, lane = row | (((d0 >> 3) & 3) << 4);
    *(uint4*)&aF[0][kt*512 + lane*8] = u;
  } else {
    for (int i = t; i < 1024; i += 512) {
      const int row = i >> 6, d0 = (i & 63) * 4;
      stage_split4(aF, row, d0, *(const float4*)((const float*)X + (size_t)(row0 + row)*256 + d0));
    }
  }
  __syncthreads();
  if (fl) k1_raw<false>(aF, seg, ntg0, kw, qw, rw1, rb1, fl, kqA, PfA, QpkA, row0, t);
  else    k1_raw<true >(aF, seg, ntg0, kw, qw, rw1, rb1, fl, kqA, PfA, QpkA, row0, t);
}

// ---------------------------------------------------------------------------
// k1 body from wfb (layer 1): 16 rows x (8 waves * NTG * 16) cols
// ---------------------------------------------------------------------------
template<bool SPLIT, int NTG>
__device__ __forceinline__ void k1_body(
    const unsigned short (&aF)[2][4096],
    const unsigned short* __restrict__ wfb, const float* __restrict__ bc,
    float* __restrict__ kq, float* __restrict__ Pf, unsigned* __restrict__ Qpk,
    int l, int row0, int ntg0, int t)
{
  const int w = t >> 6, l64 = t & 63;
  const int col = l64 & 15, quad = l64 >> 4;
  f32x4 acc[NTG];
  #pragma unroll
  for (int i = 0; i < NTG; ++i) acc[i] = (f32x4){0.f, 0.f, 0.f, 0.f};
  for (int kt = 0; kt < 8; ++kt) {
    const bf16x8 ah = *(const bf16x8*)&aF[0][kt*512 + l64*8];
    bf16x8 al;
    if (SPLIT) al = *(const bf16x8*)&aF[1][kt*512 + l64*8];
    #pragma unroll
    for (int i = 0; i < NTG; ++i) {
      const int ntg = ntg0 + w*NTG + i;
      const bf16x8 b = *(const bf16x8*)&wfb[((l*8 + kt)*64 + ntg)*512 + l64*8];
      acc[i] = __builtin_amdgcn_mfma_f32_16x16x32_bf16(ah, b, acc[i], 0, 0, 0);
      if (SPLIT) acc[i] = __builtin_amdgcn_mfma_f32_16x16x32_bf16(al, b, acc[i], 0, 0, 0);
    }
  }
  #pragma unroll
  for (int i = 0; i < NTG; ++i) {
    const int ntg = ntg0 + w*NTG + i;
    if (ntg < 32) {
      const int n = ntg*16 + col;
      #pragma unroll
      for (int r = 0; r < 4; ++r)
        kq[(size_t)(row0 + quad*4 + r)*512 + n] = acc[i][r];
    } else if (ntg < 48) {
      const int c = (ntg - 32)*16 + col;
      const float bias = bc[l*256 + c];
      #pragma unroll
      for (int r = 0; r < 4; ++r)
        Pf[(size_t)(row0 + quad*4 + r)*256 + c] = acc[i][r] + bias;
    } else {
      #pragma unroll
      for (int r = 0; r < 4; ++r) {
        const float v = acc[i][r];
        const float pv = __shfl_xor(v, 1, 64);
        if (!(col & 1)) {
          const unsigned uu = (unsigned)bfr(v) | ((unsigned)bfr(pv) << 16);
          Qpk[(size_t)(row0 + quad*4 + r)*128 + (ntg - 48)*8 + (col >> 1)] = uu;
        }
      }
    }
  }
}

// ---------------------------------------------------------------------------
// k4 core (512 thr): agg=g@rw2^T+rb2; h=LN(xin+agg); out=xin+mlp(h)
// ---------------------------------------------------------------------------
__device__ __forceinline__ void k4_gemm8(
    f32x4 acc[2], const unsigned short (&aF)[2][4096],
    const unsigned short* __restrict__ wg, int w, int l64)
{
  acc[0] = (f32x4){0.f, 0.f, 0.f, 0.f};
  acc[1] = (f32x4){0.f, 0.f, 0.f, 0.f};
  for (int kt = 0; kt < 8; ++kt) {
    const bf16x8 ah = *(const bf16x8*)&aF[0][kt*512 + l64*8];
    const bf16x8 al = *(const bf16x8*)&aF[1][kt*512 + l64*8];
    #pragma unroll
    for (int nt = 0; nt < 2; ++nt) {
      const bf16x8 b = *(const bf16x8*)&wg[((kt*16 + (w*2 + nt))*64 + l64)*8];
      acc[nt] = __builtin_amdgcn_mfma_f32_16x16x32_bf16(ah, b, acc[nt], 0, 0, 0);
      acc[nt] = __builtin_amdgcn_mfma_f32_16x16x32_bf16(al, b, acc[nt], 0, 0, 0);
    }
  }
}

template<bool ADAPT>
__device__ __forceinline__ void k4_core(
    const float* __restrict__ g, const void* __restrict__ xin, int fl,
    float* __restrict__ xout, const unsigned short* __restrict__ wg,
    const float* __restrict__ bc, int l, int row0, int t, bool writeX,
    unsigned short (&aF)[2][4096], float* bufB, float (&mv)[16][2])
{
  const int w = t >> 6, l64 = t & 63;
  const int col = l64 & 15, quad = l64 >> 4;
  const float* rb2c = bc + 512  + l*256;
  const float* lngc = bc + 1024 + l*256;
  const float* lnbc = bc + 1536 + l*256;
  const float* mb1c = bc + 2048 + l*256;
  const float* mb2c = bc + 2560 + l*256;

  for (int i = t; i < 1024; i += 512) {
    const int row = i >> 6, d0 = (i & 63) * 4;
    stage_split4(aF, row, d0, *(const float4*)&g[(size_t)(row0 + row)*256 + d0]);
  }
  if (ADAPT && fl) {
    for (int c = t; c < 2048; c += 512) {
      const int row = c >> 7, dp = c & 127;
      const unsigned u = ((const unsigned*)xin)[(size_t)(row0 + row)*128 + dp];
      bufB[row*260 + dp*2]     = __uint_as_float(u << 16);
      bufB[row*260 + dp*2 + 1] = __uint_as_float(u & 0xffff0000u);
    }
  } else {
    for (int c = t; c < 1024; c += 512) {
      const int row = c >> 6, d0 = (c & 63) * 4;
      *(float4*)&bufB[row*260 + d0] = *(const float4*)((const float*)xin + (size_t)(row0 + row)*256 + d0);
    }
  }
  __syncthreads();
  float xtr[2][4];
  #pragma unroll
  for (int nt = 0; nt < 2; ++nt) {
    const int cn = (w*2 + nt)*16 + col;
    #pragma unroll
    for (int r = 0; r < 4; ++r) xtr[nt][r] = bufB[(quad*4 + r)*260 + cn];
  }
  __syncthreads();

  f32x4 acc[2];
  k4_gemm8(acc, aF, wg, w, l64);               // GEMM1
  #pragma unroll
  for (int nt = 0; nt < 2; ++nt) {
    const int cn = (w*2 + nt)*16 + col;
    #pragma unroll
    for (int r = 0; r < 4; ++r)
      bufB[(quad*4 + r)*260 + cn] = acc[nt][r] + rb2c[cn] + xtr[nt][r];
  }
  __syncthreads();
  {                                            // LN stats
    const int row = t >> 5, part = t & 31;
    float s = 0.f, s2 = 0.f;
    #pragma unroll
    for (int kk = 0; kk < 8; ++kk) {
      const float v = bufB[row*260 + part + kk*32];
      s += v; s2 = fmaf(v, v, s2);
    }
    #pragma unroll
    for (int off = 16; off; off >>= 1) {
      s  += __shfl_xor(s, off, 32);
      s2 += __shfl_xor(s2, off, 32);
    }
    if (part == 0) {
      const float mu = s * (1.f/256.f);
      mv[row][0] = mu;
      mv[row][1] = rsqrtf(fmaf(-mu, mu, s2 * (1.f/256.f)) + 1e-5f);
    }
  }
  __syncthreads();
  for (int i = t; i < 1024; i += 512) {        // LN apply + restage
    const int row = i >> 6, d0 = (i & 63) * 4;
    float4 v = *(const float4*)&bufB[row*260 + d0];
    const float m = mv[row][0], iv = mv[row][1];
    v.x = (v.x - m)*iv*lngc[d0]   + lnbc[d0];
    v.y = (v.y - m)*iv*lngc[d0+1] + lnbc[d0+1];
    v.z = (v.z - m)*iv*lngc[d0+2] + lnbc[d0+2];
    v.w = (v.w - m)*iv*lngc[d0+3] + lnbc[d0+3];
    stage_split4(aF, row, d0, v);
  }
  __syncthreads();
  k4_gemm8(acc, aF, wg + 65536, w, l64);       // GEMM2 + gelu
  #pragma unroll
  for (int nt = 0; nt < 2; ++nt) {
    const int cn = (w*2 + nt)*16 + col;
    #pragma unroll
    for (int r = 0; r < 4; ++r)
      bufB[(quad*4 + r)*260 + cn] = gelu_e(acc[nt][r] + mb1c[cn]);
  }
  __syncthreads();
  for (int i = t; i < 1024; i += 512) {        // restage
    const int row = i >> 6, d0 = (i & 63) * 4;
    stage_split4(aF, row, d0, *(const float4*)&bufB[row*260 + d0]);
  }
  __syncthreads();
  k4_gemm8(acc, aF, wg + 2*65536, w, l64);     // GEMM3 + residual
  #pragma unroll
  for (int nt = 0; nt < 2; ++nt) {
    const int cn = (w*2 + nt)*16 + col;
    #pragma unroll
    for (int r = 0; r < 4; ++r)
      bufB[(quad*4 + r)*260 + cn] = acc[nt][r] + mb2c[cn] + xtr[nt][r];
  }
  __syncthreads();
  for (int i = t; i < 1024; i += 512) {        // x write + restage
    const int row = i >> 6, d0 = (i & 63) * 4;
    const float4 v = *(const float4*)&bufB[row*260 + d0];
    if (writeX) *(float4*)&xout[(size_t)(row0 + row)*256 + d0] = v;
    stage_split4(aF, row, d0, v);
  }
  __syncthreads();
}

// ---------------------------------------------------------------------------
// k23m: fused scores+softmax+agg (4 rows/block, 512 thr) with tile-last-arrival
// winner running the mix for its 16-row tile.
// mode 0: winner -> k4(l0, residual X) + k1(l1) -> kqB/PfB/QpkB, writes x
// mode 1: winner -> k4(l1, residual x) + column sums -> ssacc; batch-last
//         winner runs the head.
// grid 512 (b*16 + qd), 512 thr.
// ---------------------------------------------------------------------------
__global__ __launch_bounds__(512) void k23m(
    const float* __restrict__ kq, const float* __restrict__ Pf,
    const unsigned* __restrict__ Qpk, float* __restrict__ g,
    const void* __restrict__ X, float* __restrict__ x,
    const unsigned short* __restrict__ w3b, const unsigned short* __restrict__ wfb,
    const float* __restrict__ bc, const float* __restrict__ wh,
    float* __restrict__ kqO, float* __restrict__ PfO, unsigned* __restrict__ QpkO,
    float* __restrict__ ssacc, unsigned* __restrict__ cnts,
    void* __restrict__ out, int mode)
{
  __shared__ __align__(16) char smem[33280];
  __shared__ float mv[16][2];
  __shared__ int winf;
  const int fl = block_detect(X);
  const int t = threadIdx.x;
  const int b = (int)blockIdx.x >> 4, qd = (int)blockIdx.x & 15;
  const int base = b << 6, i0 = qd * 4;
  float* qs  = (float*)smem;              // [4][256]
  float* scp = qs + 1024;                 // [4][64]
  float* als = scp + 256;                 // [4][64]

  for (int i = t; i < 1024; i += 512)
    qs[i] = kq[(size_t)(base + i0 + (i >> 8))*512 + 256 + (i & 255)];
  __syncthreads();
  {  // scores: 8 waves, wave w -> (row = w&3, j-half = w>>2); lane=(dh<<5)|jl
    const int w = t >> 6, lane = t & 63;
    const int r = w & 3, jh = w >> 2;
    const int jl = lane & 31, dh = lane >> 5;
    const int j = jh*32 + jl;
    const float* krow = kq + (size_t)(base + j)*512 + dh*128;
    const float* qp = qs + r*256 + dh*128;
    float s = 0.f;
    for (int dd = 0; dd < 128; dd += 4) {
      const float4 kv = *(const float4*)&krow[dd];
      const float4 qv = *(const float4*)&qp[dd];
      s = fmaf(kv.x, qv.x, s); s = fmaf(kv.y, qv.y, s);
      s = fmaf(kv.z, qv.z, s); s = fmaf(kv.w, qv.w, s);
    }
    s += __shfl_xor(s, 32, 64);
    if (dh == 0) scp[r*64 + j] = s * 0.0625f;
  }
  __syncthreads();
  if (t < 256) {    // softmax: 4 rows, one wave each
    const int row = t >> 6, j = t & 63;
    float s = scp[row*64 + j];
    float m = s;
    #pragma unroll
    for (int off = 32; off; off >>= 1) m = fmaxf(m, __shfl_xor(m, off, 64));
    const float e = __expf(s - m);
    float ss = e;
    #pragma unroll
    for (int off = 32; off; off >>= 1) ss += __shfl_xor(ss, off, 64);
    als[row*64 + j] = e / ss;
  }
  __syncthreads();
  {  // aggregation: rg = t>>7 -> row, cp col-pair
    const int rg = t >> 7, cp = t & 127;
    const int r = base + i0 + rg;
    const float2 P = *(const float2*)&Pf[(size_t)r*256 + cp*2];
    const float A0 = -1.702f * P.x, A1 = -1.702f * P.y;
    const float* ap = als + rg*64;
    const unsigned* qp = Qpk + (size_t)base*128 + cp;
    float acc0 = 0.f, acc1 = 0.f;
    #pragma unroll 8
    for (int j = 0; j < 64; ++j) {
      const unsigned u = qp[j*128];
      const float wgt = ap[j];
      const float q0 = __uint_as_float(u << 16);
      const float q1 = __uint_as_float(u & 0xffff0000u);
      const float s0 = __builtin_amdgcn_rcpf(1.f + __expf(fmaf(1.702f, q0, A0)));
      const float s1 = __builtin_amdgcn_rcpf(1.f + __expf(fmaf(1.702f, q1, A1)));
      acc0 = fmaf(wgt * (P.x - q0), s0, acc0);
      acc1 = fmaf(wgt * (P.y - q1), s1, acc1);
    }
    *(float2*)&g[(size_t)r*256 + cp*2] = make_float2(acc0, acc1);
  }
  // ---- tile last-arrival
  const int rt = (int)blockIdx.x >> 2;        // 16-row tile id (b*4 + qd>>2)
  __syncthreads();
  if (t == 0) {
    __threadfence();                          // release g writes
    winf = (atomicAdd(&cnts[(mode ? 128 : 0) + rt], 1u) == 3u);
  }
  __syncthreads();
  if (!winf) return;
  __threadfence();                            // acquire siblings' g writes
  __syncthreads();

  auto& aF = *(unsigned short(*)[2][4096])smem;
  float* bufB = (float*)(smem + 16384);
  const int row0 = rt * 16;
  if (mode == 0) {
    k4_core<true>(g, X, fl, x, w3b, bc, 0, row0, t, true, aF, bufB, mv);
    k1_body<true, 8>(aF, wfb, bc, kqO, PfO, QpkO, 1, row0, 0, t);
    return;
  }
  // mode 1: final mix + head
  k4_core<false>(g, x, 0, x, w3b + 3*65536, bc, 1, row0, t, false, aF, bufB, mv);
  if (t < 256) {
    float cs = 0.f;
    #pragma unroll
    for (int r = 0; r < 16; ++r) cs += bufB[r*260 + t];
    atomicAdd(&ssacc[b*256 + t], cs);
  }
  __syncthreads();
  if (t == 0) winf = (atomicAdd(&cnts[256 + b], 1u) == 3u);
  __syncthreads();
  if (!winf) return;
  float* ss = bufB;
  float* hh = bufB + 256;
  if (t < 256)
    ss[t] = __hip_atomic_load(&ssacc[b*256 + t], __ATOMIC_RELAXED, __HIP_MEMORY_SCOPE_AGENT);
  __syncthreads();
  if (t < 128) {
    float acc = bc[3072 + t];
    const float* projT = wh;
    for (int d = 0; d < 256; ++d) acc = fmaf(ss[d], projT[d*128 + t], acc);
    hh[t] = gelu_e(acc);
  }
  __syncthreads();
  if (t < 256) {
    float v; int oidx;
    if (t < 128) {
      float acc = bc[3200 + t];
      const float* muT = wh + 32768;
      for (int c = 0; c < 128; ++c) acc = fmaf(hh[c], muT[c*128 + t], acc);
      v = acc; oidx = b*128 + t;
    } else {
      const int u = t - 128;
      float acc = bc[3328 + u];
      const float* spT = wh + 49152;
      for (int c = 0; c < 128; ++c) acc = fmaf(hh[c], spT[c*128 + u], acc);
      v = (acc > 20.f) ? acc : log1pf(__expf(acc));
      oidx = 4096 + b*128 + u;
    }
    if (fl) ((bf16*)out)[oidx] = __float2bfloat16(v);
    else    ((float*)out)[oidx] = v;
  }
}

// ---------------------------------------------------------------------------
extern "C" void kernel_launch(void* const* d_in, const int* in_sizes, int n_in,
                              void* d_out, int out_size, void* d_ws, size_t ws_size,
                              hipStream_t stream)
{
  (void)in_sizes; (void)n_in; (void)out_size; (void)ws_size;
  float* ws    = (float*)d_ws;
  float* x     = ws + 16;                          // 524288
  float* kqA   = x + 524288;                       // 1048576
  float* PfA   = kqA + 1048576;                    // 524288
  unsigned* QpkA = (unsigned*)(PfA + 524288);      // 262144
  float* kqB   = (float*)(QpkA + 262144);          // 1048576
  float* PfB   = kqB + 1048576;                    // 524288
  unsigned* QpkB = (unsigned*)(PfB + 524288);      // 262144
  float* g     = (float*)(QpkB + 262144);          // 524288
  unsigned short* wfb = (unsigned short*)(g + 524288);   // 2*8*64*512 shorts
  unsigned short* w3b = wfb + 524288;              // 393216 shorts
  float* wh    = (float*)(w3b + 393216);           // 65536
  float* bc    = wh + 65536;                       // 3456 (pad 4096)
  float* ssacc = bc + 4096;                        // 8192
  unsigned* cnts = (unsigned*)(ssacc + 8192);      // 288 (cntA128|cntB128|cntH32)

  fusedA<<<dim3(593), dim3(512), 0, stream>>>(
      d_in[0], d_in[1], d_in[2], d_in[3], d_in[5], d_in[9], d_in[11],
      d_in[13], d_in[15], d_in[17],
      d_in[4], d_in[6], d_in[7], d_in[8], d_in[10], d_in[12],
      d_in[14], d_in[16], d_in[18],
      wfb, w3b, wh, bc, cnts, ssacc, kqA, PfA, QpkA);
  k23m<<<dim3(512), dim3(512), 0, stream>>>(
      kqA, PfA, QpkA, g, d_in[0], x, w3b, wfb, bc, wh,
      kqB, PfB, QpkB, ssacc, cnts, (void*)d_out, 0);
  k23m<<<dim3(512), dim3(512), 0, stream>>>(
      kqB, PfB, QpkB, g, d_in[0], x, w3b, wfb, bc, wh,
      kqB, PfB, QpkB, ssacc, cnts, (void*)d_out, 1);
}

// Round 12
// 208.105 us; speedup vs baseline: 1.5822x; 1.5822x over previous
//
#include <hip/hip_runtime.h>
#include <hip/hip_bf16.h>

// B=32, K=64, D=256, LS=128, rows = 2048
// R12 = exact revert to R9 (best measured: 208.8 us, absmax 0.5).

using bf16 = __hip_bfloat16;
typedef short bf16x8 __attribute__((ext_vector_type(8)));
typedef float f32x4 __attribute__((ext_vector_type(4)));

__device__ __forceinline__ float bfu(unsigned short u) { return __uint_as_float(((unsigned)u) << 16); }

__device__ __forceinline__ unsigned short bfr(float v) {   // RNE fp32->bf16 bits
  unsigned u = __float_as_uint(v);
  u += 0x7FFFu + ((u >> 16) & 1u);
  return (unsigned short)(u >> 16);
}

__device__ __forceinline__ float gelu_e(float x) {
  return 0.5f * x * (1.0f + erff(x * 0.7071067811865475f));
}

__device__ __forceinline__ float load_f(const void* p, int i, int fl) {
  if (fl) return bfu(((const unsigned short*)p)[i]);
  return ((const float*)p)[i];
}

// per-block inline dtype detect: 1 = inputs are bf16
__device__ __forceinline__ int block_detect(const void* X) {
  __shared__ int bad_s;
  if (threadIdx.x == 0) bad_s = 0;
  __syncthreads();
  if (threadIdx.x < 256) {
    const float v = bfu(((const unsigned short*)X)[threadIdx.x]);
    if (!(fabsf(v) < 1e6f)) atomicOr(&bad_s, 1);
  }
  __syncthreads();
  return bad_s ? 0 : 1;
}

// stage one float4 (row, d0) into hi/lo MFMA A-fragments
__device__ __forceinline__ void stage_split4(unsigned short (&aF)[2][4096], int row, int d0, float4 v) {
  ushort4 h, lo;
  h.x = bfr(v.x); h.y = bfr(v.y); h.z = bfr(v.z); h.w = bfr(v.w);
  lo.x = bfr(v.x - bfu(h.x)); lo.y = bfr(v.y - bfu(h.y));
  lo.z = bfr(v.z - bfu(h.z)); lo.w = bfr(v.w - bfu(h.w));
  const int kt = d0 >> 5, lane = row | (((d0 >> 3) & 3) << 4), j = d0 & 7;
  *(ushort4*)&aF[0][kt*512 + lane*8 + j] = h;
  *(ushort4*)&aF[1][kt*512 + lane*8 + j] = lo;
}

// ---------------------------------------------------------------------------
// prep (89 blocks x 256 thr): weights -> ws
// ---------------------------------------------------------------------------
__global__ __launch_bounds__(256) void prep_kernel(
    const void* __restrict__ X, const void* __restrict__ kw, const void* __restrict__ qw,
    const void* __restrict__ rw1, const void* __restrict__ rw2, const void* __restrict__ mw1,
    const void* __restrict__ mw2, const void* __restrict__ pw, const void* __restrict__ muw,
    const void* __restrict__ spw,
    const void* __restrict__ rb1, const void* __restrict__ rb2, const void* __restrict__ lng,
    const void* __restrict__ lnb, const void* __restrict__ mb1, const void* __restrict__ mb2,
    const void* __restrict__ pb, const void* __restrict__ mub, const void* __restrict__ spb,
    unsigned short* __restrict__ wfb, unsigned short* __restrict__ w3b,
    float* __restrict__ wh, float* __restrict__ bc)
{
  __shared__ __align__(16) char psm[65536];
  const int fl = block_detect(X);
  const int t = threadIdx.x;
  int blk = blockIdx.x;

  if (blk < 16) {   // ---- A: wfb (l,kt)
    unsigned short* ls = (unsigned short*)psm;
    unsigned* lsu = (unsigned*)psm;
    const int l = blk >> 3, kt = blk & 7;
    if (fl) {
      #pragma unroll
      for (int s = 0; s < 4; ++s) {
        const unsigned* sp = (const unsigned*)((s == 0) ? kw : (s == 1) ? qw : rw1);
        const int rstr = (s < 2) ? 128 : 256;
        const int coff = ((s == 3) ? 128 : 0) + kt*16;
        for (int i = t; i < 4096; i += 256) {
          const int e = i >> 4, d2 = i & 15;
          lsu[s*4096 + i] = sp[(l*256 + e)*rstr + coff + d2];
        }
      }
    } else {
      #pragma unroll
      for (int s = 0; s < 4; ++s) {
        const float* sp = (const float*)((s == 0) ? kw : (s == 1) ? qw : rw1);
        const int rstr = (s < 2) ? 256 : 512;
        const int coff = ((s == 3) ? 256 : 0) + kt*32;
        for (int i = t; i < 4096; i += 256) {
          const int e = i >> 4, d2 = i & 15;
          const float f0 = sp[(l*256 + e)*rstr + coff + d2*2];
          const float f1 = sp[(l*256 + e)*rstr + coff + d2*2 + 1];
          lsu[s*4096 + i] = (unsigned)bfr(f0) | ((unsigned)bfr(f1) << 16);
        }
      }
    }
    __syncthreads();
    unsigned* outp = (unsigned*)wfb + (l*8 + kt)*16384;
    for (int f2 = t; f2 < 16384; f2 += 256) {
      const int j2 = f2 & 3, lane = (f2 >> 2) & 63, ntg = f2 >> 8;
      const int seg = ntg >> 4;
      const int e = (ntg & 15)*16 + (lane & 15);
      const int dl = ((lane >> 4) & 3)*8 + j2*2;
      unsigned short r0 = ls[seg*8192 + e*32 + dl];
      unsigned short r1 = ls[seg*8192 + e*32 + dl + 1];
      if (seg == 1) { r0 = bfr(bfu(r0)*0.0625f); r1 = bfr(bfu(r1)*0.0625f); }
      else if (seg == 2) {
        const unsigned short w0 = ls[3*8192 + e*32 + dl];
        const unsigned short w1 = ls[3*8192 + e*32 + dl + 1];
        r0 = bfr(bfu(r0) + bfu(w0)); r1 = bfr(bfu(r1) + bfu(w1));
      }
      outp[f2] = (unsigned)r0 | ((unsigned)r1 << 16);
    }
    return;
  }
  blk -= 16;
  if (blk < 48) {   // ---- B: w3b (l,gm,kt)
    unsigned short* ls = (unsigned short*)psm;
    unsigned* lsu = (unsigned*)psm;
    const int l3 = blk >> 3, kt = blk & 7;
    const int l = l3 / 3, gm = l3 % 3;
    const void* src = (gm == 0) ? rw2 : (gm == 1) ? mw1 : mw2;
    if (fl) {
      const unsigned* sp = (const unsigned*)src;
      for (int i = t; i < 4096; i += 256) {
        const int e = i >> 4, d2 = i & 15;
        lsu[i] = sp[(l*256 + e)*128 + kt*16 + d2];
      }
    } else {
      const float* sp = (const float*)src;
      for (int i = t; i < 4096; i += 256) {
        const int e = i >> 4, d2 = i & 15;
        const float f0 = sp[(l*256 + e)*256 + kt*32 + d2*2];
        const float f1 = sp[(l*256 + e)*256 + kt*32 + d2*2 + 1];
        lsu[i] = (unsigned)bfr(f0) | ((unsigned)bfr(f1) << 16);
      }
    }
    __syncthreads();
    unsigned* outp = (unsigned*)w3b + (l3*8 + kt)*4096;
    for (int f2 = t; f2 < 4096; f2 += 256) {
      const int j2 = f2 & 3, lane = (f2 >> 2) & 63, nt = f2 >> 8;
      const int e = nt*16 + (lane & 15);
      const int dl = ((lane >> 4) & 3)*8 + j2*2;
      outp[f2] = (unsigned)ls[e*32 + dl] | ((unsigned)ls[e*32 + dl + 1] << 16);
    }
    return;
  }
  blk -= 48;
  if (blk < 24) {   // ---- D: wh transposes
    float* lsf = (float*)psm;
    if (blk < 8) {          // projT
      const int l0 = blk*16;
      if (fl) {
        const unsigned* sp = (const unsigned*)pw;
        for (int i = t; i < 2048; i += 256) {
          const int ll = i >> 7, d2 = i & 127;
          const unsigned u = sp[(l0 + ll)*128 + d2];
          lsf[ll*256 + d2*2]     = __uint_as_float(u << 16);
          lsf[ll*256 + d2*2 + 1] = __uint_as_float(u & 0xffff0000u);
        }
      } else {
        const float* sp = (const float*)pw;
        for (int i = t; i < 4096; i += 256) {
          const int ll = i >> 8, d = i & 255;
          lsf[ll*256 + d] = sp[(l0 + ll)*256 + d];
        }
      }
      __syncthreads();
      for (int i = t; i < 4096; i += 256) {
        const int d = i >> 4, ll = i & 15;
        wh[d*128 + l0 + ll] = lsf[ll*256 + d];
      }
    } else {                // muT / spT
      const int grp2 = blk - 8;
      const int isSp = grp2 >> 3;
      const int l0 = (grp2 & 7)*16;
      const void* src = isSp ? spw : muw;
      const int off = isSp ? 49152 : 32768;
      if (fl) {
        const unsigned* sp = (const unsigned*)src;
        for (int i = t; i < 1024; i += 256) {
          const int ll = i >> 6, c2 = i & 63;
          const unsigned u = sp[(l0 + ll)*64 + c2];
          lsf[ll*128 + c2*2]     = __uint_as_float(u << 16);
          lsf[ll*128 + c2*2 + 1] = __uint_as_float(u & 0xffff0000u);
        }
      } else {
        const float* sp = (const float*)src;
        for (int i = t; i < 2048; i += 256) {
          const int ll = i >> 7, c = i & 127;
          lsf[ll*128 + c] = sp[(l0 + ll)*128 + c];
        }
      }
      __syncthreads();
      for (int i = t; i < 2048; i += 256) {
        const int c = i >> 4, ll = i & 15;
        wh[off + c*128 + l0 + ll] = lsf[ll*128 + c];
      }
    }
    return;
  }
  // ---- E: bc
  for (int i = t; i < 3456; i += 256) {
    const void* src; int off;
    if (i < 512)       { src = rb1; off = i; }
    else if (i < 1024) { src = rb2; off = i - 512; }
    else if (i < 1536) { src = lng; off = i - 1024; }
    else if (i < 2048) { src = lnb; off = i - 1536; }
    else if (i < 2560) { src = mb1; off = i - 2048; }
    else if (i < 3072) { src = mb2; off = i - 2560; }
    else if (i < 3200) { src = pb;  off = i - 3072; }
    else if (i < 3328) { src = mub; off = i - 3200; }
    else               { src = spb; off = i - 3328; }
    bc[i] = load_f(src, off, fl);
  }
}

// ---------------------------------------------------------------------------
// k1 body: 16 rows x (waves*NTG*16) cols from staged A-frags
// ---------------------------------------------------------------------------
template<bool SPLIT, int NTG>
__device__ __forceinline__ void k1_body(
    const unsigned short (&aF)[2][4096],
    const unsigned short* __restrict__ wfb, const float* __restrict__ bc,
    float* __restrict__ kq, float* __restrict__ Pf, unsigned* __restrict__ Qpk,
    int l, int row0, int ntg0, int t)
{
  const int w = t >> 6, l64 = t & 63;
  const int col = l64 & 15, quad = l64 >> 4;
  f32x4 acc[NTG];
  #pragma unroll
  for (int i = 0; i < NTG; ++i) acc[i] = (f32x4){0.f, 0.f, 0.f, 0.f};
  for (int kt = 0; kt < 8; ++kt) {
    const bf16x8 ah = *(const bf16x8*)&aF[0][kt*512 + l64*8];
    bf16x8 al;
    if (SPLIT) al = *(const bf16x8*)&aF[1][kt*512 + l64*8];
    #pragma unroll
    for (int i = 0; i < NTG; ++i) {
      const int ntg = ntg0 + w*NTG + i;
      const bf16x8 b = *(const bf16x8*)&wfb[((l*8 + kt)*64 + ntg)*512 + l64*8];
      acc[i] = __builtin_amdgcn_mfma_f32_16x16x32_bf16(ah, b, acc[i], 0, 0, 0);
      if (SPLIT) acc[i] = __builtin_amdgcn_mfma_f32_16x16x32_bf16(al, b, acc[i], 0, 0, 0);
    }
  }
  #pragma unroll
  for (int i = 0; i < NTG; ++i) {
    const int ntg = ntg0 + w*NTG + i;
    if (ntg < 32) {
      const int n = ntg*16 + col;
      #pragma unroll
      for (int r = 0; r < 4; ++r)
        kq[(size_t)(row0 + quad*4 + r)*512 + n] = acc[i][r];
    } else if (ntg < 48) {
      const int c = (ntg - 32)*16 + col;
      const float bias = bc[l*256 + c];
      #pragma unroll
      for (int r = 0; r < 4; ++r)
        Pf[(size_t)(row0 + quad*4 + r)*256 + c] = acc[i][r] + bias;
    } else {
      #pragma unroll
      for (int r = 0; r < 4; ++r) {
        const float v = acc[i][r];
        const float pv = __shfl_xor(v, 1, 64);
        if (!(col & 1)) {
          const unsigned uu = (unsigned)bfr(v) | ((unsigned)bfr(pv) << 16);
          Qpk[(size_t)(row0 + quad*4 + r)*128 + (ntg - 48)*8 + (col >> 1)] = uu;
        }
      }
    }
  }
}

// ---------------------------------------------------------------------------
// k1 layer-0: 512 blocks (128 m x 4 n) x 256 thr
// ---------------------------------------------------------------------------
__global__ __launch_bounds__(256) void k1l0(
    const void* __restrict__ X, const unsigned short* __restrict__ wfb,
    const float* __restrict__ bc, float* __restrict__ kq, float* __restrict__ Pf,
    unsigned* __restrict__ Qpk)
{
  const int fl = block_detect(X);
  __shared__ __align__(16) unsigned short aF[2][4096];
  const int t = threadIdx.x;
  const int mb = (int)blockIdx.x >> 2, nb4 = (int)blockIdx.x & 3;
  const int row0 = mb * 16, ntg0 = nb4 * 16;
  if (fl) {
    for (int i = t; i < 512; i += 256) {
      const int row = i >> 5, d0 = (i & 31) * 8;
      const uint4 u = *(const uint4*)((const unsigned*)X + (size_t)(row0 + row)*128 + (i & 31)*4);
      const int kt = d0 >> 5, lane = row | (((d0 >> 3) & 3) << 4);
      *(uint4*)&aF[0][kt*512 + lane*8] = u;
    }
  } else {
    for (int i = t; i < 1024; i += 256) {
      const int row = i >> 6, d0 = (i & 63) * 4;
      stage_split4(aF, row, d0, *(const float4*)((const float*)X + (size_t)(row0 + row)*256 + d0));
    }
  }
  __syncthreads();
  if (fl) k1_body<false, 4>(aF, wfb, bc, kq, Pf, Qpk, 0, row0, ntg0, t);
  else    k1_body<true,  4>(aF, wfb, bc, kq, Pf, Qpk, 0, row0, ntg0, t);
}

// ---------------------------------------------------------------------------
// k23: fused scores + softmax + gelu-weighted aggregation
// grid 1024 (b, i-pair), 256 thr / 4 waves; Q read from L2
// ---------------------------------------------------------------------------
__global__ __launch_bounds__(256) void k23_attn(
    const float* __restrict__ kq, const float* __restrict__ Pf,
    const unsigned* __restrict__ Qpk, float* __restrict__ g)
{
  __shared__ float qs[2][256];
  __shared__ float scp[2][64];
  __shared__ float als[2][64];
  const int t = threadIdx.x;
  const int b = (int)blockIdx.x >> 5, ip = (int)blockIdx.x & 31;
  const int base = b << 6, i0 = ip * 2;
  for (int i = t; i < 512; i += 256)
    qs[i >> 8][i & 255] = kq[(size_t)(base + i0 + (i >> 8))*512 + 256 + (i & 255)];
  __syncthreads();
  {
    const int w = t >> 6, lane = t & 63;
    const int jl = lane & 15, part = lane >> 4;
    const int j = w*16 + jl;
    const float* krow = kq + (size_t)(base + j)*512 + part*64;
    const float* q0p = &qs[0][part*64];
    const float* q1p = &qs[1][part*64];
    float s0 = 0.f, s1 = 0.f;
    for (int dd = 0; dd < 64; dd += 4) {
      const float4 kv = *(const float4*)&krow[dd];
      const float4 q0 = *(const float4*)&q0p[dd];
      const float4 q1 = *(const float4*)&q1p[dd];
      s0 = fmaf(kv.x, q0.x, s0); s0 = fmaf(kv.y, q0.y, s0);
      s0 = fmaf(kv.z, q0.z, s0); s0 = fmaf(kv.w, q0.w, s0);
      s1 = fmaf(kv.x, q1.x, s1); s1 = fmaf(kv.y, q1.y, s1);
      s1 = fmaf(kv.z, q1.z, s1); s1 = fmaf(kv.w, q1.w, s1);
    }
    s0 += __shfl_xor(s0, 16, 64); s0 += __shfl_xor(s0, 32, 64);
    s1 += __shfl_xor(s1, 16, 64); s1 += __shfl_xor(s1, 32, 64);
    if (part == 0) { scp[0][j] = s0; scp[1][j] = s1; }
  }
  __syncthreads();
  if (t < 128) {
    const int row = t >> 6, j = t & 63;
    float s = scp[row][j];
    float m = s;
    #pragma unroll
    for (int off = 32; off; off >>= 1) m = fmaxf(m, __shfl_xor(m, off, 64));
    const float e = __expf(s - m);
    float ss = e;
    #pragma unroll
    for (int off = 32; off; off >>= 1) ss += __shfl_xor(ss, off, 64);
    als[row][j] = e / ss;
  }
  __syncthreads();
  const int rg = t >> 7, cp = t & 127;
  const int r = base + i0 + rg;
  const float2 P = *(const float2*)&Pf[(size_t)r*256 + cp*2];
  const float A0 = -1.702f * P.x, A1 = -1.702f * P.y;
  const float* ap = &als[rg][0];
  const unsigned* qp = Qpk + (size_t)base*128 + cp;
  float acc0 = 0.f, acc1 = 0.f;
  #pragma unroll 8
  for (int j = 0; j < 64; ++j) {
    const unsigned u = qp[j*128];
    const float wgt = ap[j];
    const float q0 = __uint_as_float(u << 16);
    const float q1 = __uint_as_float(u & 0xffff0000u);
    const float s0 = __builtin_amdgcn_rcpf(1.f + __expf(fmaf(1.702f, q0, A0)));
    const float s1 = __builtin_amdgcn_rcpf(1.f + __expf(fmaf(1.702f, q1, A1)));
    acc0 = fmaf(wgt * (P.x - q0), s0, acc0);
    acc1 = fmaf(wgt * (P.y - q1), s1, acc1);
  }
  *(float2*)&g[(size_t)r*256 + cp*2] = make_float2(acc0, acc1);
}

// ---------------------------------------------------------------------------
// k4 core (512 thr): agg=g@rw2^T+rb2; h=LN(xin+agg); out=xin+mlp(h)
// ---------------------------------------------------------------------------
__device__ __forceinline__ void k4_gemm8(
    f32x4 acc[2], const unsigned short (&aF)[2][4096],
    const unsigned short* __restrict__ wg, int w, int l64)
{
  acc[0] = (f32x4){0.f, 0.f, 0.f, 0.f};
  acc[1] = (f32x4){0.f, 0.f, 0.f, 0.f};
  for (int kt = 0; kt < 8; ++kt) {
    const bf16x8 ah = *(const bf16x8*)&aF[0][kt*512 + l64*8];
    const bf16x8 al = *(const bf16x8*)&aF[1][kt*512 + l64*8];
    #pragma unroll
    for (int nt = 0; nt < 2; ++nt) {
      const bf16x8 b = *(const bf16x8*)&wg[((kt*16 + (w*2 + nt))*64 + l64)*8];
      acc[nt] = __builtin_amdgcn_mfma_f32_16x16x32_bf16(ah, b, acc[nt], 0, 0, 0);
      acc[nt] = __builtin_amdgcn_mfma_f32_16x16x32_bf16(al, b, acc[nt], 0, 0, 0);
    }
  }
}

template<bool ADAPT, bool TAIL, int NR>
__device__ __forceinline__ void k4_core(
    const float* __restrict__ g, const void* __restrict__ xin, int fl,
    float* __restrict__ xout, const unsigned short* __restrict__ wg,
    const float* __restrict__ bc, int l, int row0, int t, bool writeX,
    unsigned short (&aF)[2][4096], float* bufB, float (&mv)[16][2])
{
  const int w = t >> 6, l64 = t & 63;
  const int col = l64 & 15, quad = l64 >> 4;
  const float* rb2c = bc + 512  + l*256;
  const float* lngc = bc + 1024 + l*256;
  const float* lnbc = bc + 1536 + l*256;
  const float* mb1c = bc + 2048 + l*256;
  const float* mb2c = bc + 2560 + l*256;

  for (int i = t; i < NR*64; i += 512) {
    const int row = i >> 6, d0 = (i & 63) * 4;
    stage_split4(aF, row, d0, *(const float4*)&g[(size_t)(row0 + row)*256 + d0]);
  }
  if (ADAPT && fl) {
    for (int c = t; c < NR*128; c += 512) {
      const int row = c >> 7, dp = c & 127;
      const unsigned u = ((const unsigned*)xin)[(size_t)(row0 + row)*128 + dp];
      bufB[row*260 + dp*2]     = __uint_as_float(u << 16);
      bufB[row*260 + dp*2 + 1] = __uint_as_float(u & 0xffff0000u);
    }
  } else {
    for (int c = t; c < NR*64; c += 512) {
      const int row = c >> 6, d0 = (c & 63) * 4;
      *(float4*)&bufB[row*260 + d0] = *(const float4*)((const float*)xin + (size_t)(row0 + row)*256 + d0);
    }
  }
  __syncthreads();
  float xtr[2][4];
  #pragma unroll
  for (int nt = 0; nt < 2; ++nt) {
    const int cn = (w*2 + nt)*16 + col;
    #pragma unroll
    for (int r = 0; r < 4; ++r) xtr[nt][r] = bufB[(quad*4 + r)*260 + cn];
  }
  __syncthreads();

  f32x4 acc[2];
  k4_gemm8(acc, aF, wg, w, l64);               // GEMM1
  #pragma unroll
  for (int nt = 0; nt < 2; ++nt) {
    const int cn = (w*2 + nt)*16 + col;
    #pragma unroll
    for (int r = 0; r < 4; ++r)
      bufB[(quad*4 + r)*260 + cn] = acc[nt][r] + rb2c[cn] + xtr[nt][r];
  }
  __syncthreads();
  {                                            // LN stats
    const int row = t >> 5, part = t & 31;
    if (row < NR) {
      float s = 0.f, s2 = 0.f;
      #pragma unroll
      for (int kk = 0; kk < 8; ++kk) {
        const float v = bufB[row*260 + part + kk*32];
        s += v; s2 = fmaf(v, v, s2);
      }
      #pragma unroll
      for (int off = 16; off; off >>= 1) {
        s  += __shfl_xor(s, off, 32);
        s2 += __shfl_xor(s2, off, 32);
      }
      if (part == 0) {
        const float mu = s * (1.f/256.f);
        mv[row][0] = mu;
        mv[row][1] = rsqrtf(fmaf(-mu, mu, s2 * (1.f/256.f)) + 1e-5f);
      }
    }
  }
  __syncthreads();
  for (int i = t; i < NR*64; i += 512) {       // LN apply + restage
    const int row = i >> 6, d0 = (i & 63) * 4;
    float4 v = *(const float4*)&bufB[row*260 + d0];
    const float m = mv[row][0], iv = mv[row][1];
    v.x = (v.x - m)*iv*lngc[d0]   + lnbc[d0];
    v.y = (v.y - m)*iv*lngc[d0+1] + lnbc[d0+1];
    v.z = (v.z - m)*iv*lngc[d0+2] + lnbc[d0+2];
    v.w = (v.w - m)*iv*lngc[d0+3] + lnbc[d0+3];
    stage_split4(aF, row, d0, v);
  }
  __syncthreads();
  k4_gemm8(acc, aF, wg + 65536, w, l64);       // GEMM2 + gelu
  #pragma unroll
  for (int nt = 0; nt < 2; ++nt) {
    const int cn = (w*2 + nt)*16 + col;
    #pragma unroll
    for (int r = 0; r < 4; ++r)
      if (quad*4 + r < NR)
        bufB[(quad*4 + r)*260 + cn] = gelu_e(acc[nt][r] + mb1c[cn]);
  }
  __syncthreads();
  for (int i = t; i < NR*64; i += 512) {       // restage
    const int row = i >> 6, d0 = (i & 63) * 4;
    stage_split4(aF, row, d0, *(const float4*)&bufB[row*260 + d0]);
  }
  __syncthreads();
  k4_gemm8(acc, aF, wg + 2*65536, w, l64);     // GEMM3 + residual
  if (TAIL) {
    #pragma unroll
    for (int nt = 0; nt < 2; ++nt) {
      const int cn = (w*2 + nt)*16 + col;
      #pragma unroll
      for (int r = 0; r < 4; ++r)
        bufB[(quad*4 + r)*260 + cn] = acc[nt][r] + mb2c[cn] + xtr[nt][r];
    }
    __syncthreads();
    for (int i = t; i < NR*64; i += 512) {     // coalesced x write + restage
      const int row = i >> 6, d0 = (i & 63) * 4;
      const float4 v = *(const float4*)&bufB[row*260 + d0];
      if (writeX) *(float4*)&xout[(size_t)(row0 + row)*256 + d0] = v;
      stage_split4(aF, row, d0, v);
    }
    __syncthreads();
  } else {
    #pragma unroll
    for (int nt = 0; nt < 2; ++nt) {
      const int cn = (w*2 + nt)*16 + col;
      #pragma unroll
      for (int r = 0; r < 4; ++r)
        if (quad*4 + r < NR)
          xout[(size_t)(row0 + quad*4 + r)*256 + cn] = acc[nt][r] + mb2c[cn] + xtr[nt][r];
    }
  }
}

// k41: layer-0 mix + layer-1 k1; 256 blocks (128 row-tiles x 2 parity), 512 thr
__global__ __launch_bounds__(512) void k41_mix_kq(
    const float* __restrict__ g, const unsigned short* __restrict__ w3b,
    const unsigned short* __restrict__ wfb, const float* __restrict__ bc,
    const void* __restrict__ X, float* __restrict__ x,
    float* __restrict__ kq, float* __restrict__ Pf, unsigned* __restrict__ Qpk)
{
  const int fl = block_detect(X);
  __shared__ __align__(16) unsigned short aF[2][4096];
  __shared__ float bufB[16*260];
  __shared__ float mv[16][2];
  const int t = threadIdx.x;
  const int rb = (int)blockIdx.x >> 1, parity = (int)blockIdx.x & 1;
  const int row0 = rb * 16;
  k4_core<true, true, 16>(g, X, fl, x, w3b, bc, 0, row0, t, parity == 0, aF, bufB, mv);
  k1_body<true, 4>(aF, wfb, bc, kq, Pf, Qpk, 1, row0, parity*32, t);
}

// k4fin: layer-1 mix; 256 blocks x 8 rows, 512 thr
__global__ __launch_bounds__(512) void k4_fin(
    const float* __restrict__ g, const unsigned short* __restrict__ w3b,
    const float* __restrict__ bc, float* __restrict__ x)
{
  __shared__ __align__(16) unsigned short aF[2][4096];
  __shared__ float bufB[16*260];
  __shared__ float mv[16][2];
  const int t = threadIdx.x;
  const int row0 = blockIdx.x * 8;
  k4_core<false, false, 8>(g, x, 0, x, w3b + 3*65536, bc, 1, row0, t, true, aF, bufB, mv);
}

// ---------------------------------------------------------------------------
// k5: s=sum_K x ; h=gelu(s@projT+pb) ; mu=h@muT+mb ; scale=softplus(h@spT+sb)
// ---------------------------------------------------------------------------
__global__ __launch_bounds__(256) void k5_head(
    const float* __restrict__ x, const float* __restrict__ wh,
    const float* __restrict__ bc, const void* __restrict__ X,
    void* __restrict__ out)
{
  const int fl = block_detect(X);
  __shared__ float ss[256];
  __shared__ float hh[128];
  const int b = blockIdx.x, t = threadIdx.x;
  float s = 0.f;
  for (int i = 0; i < 64; ++i) s += x[(size_t)((b << 6) + i)*256 + t];
  ss[t] = s;
  __syncthreads();
  if (t < 128) {
    float acc = bc[3072 + t];
    const float* projT = wh;
    for (int d = 0; d < 256; ++d) acc = fmaf(ss[d], projT[d*128 + t], acc);
    hh[t] = gelu_e(acc);
  }
  __syncthreads();
  float v; int oidx;
  if (t < 128) {
    float acc = bc[3200 + t];
    const float* muT = wh + 32768;
    for (int c = 0; c < 128; ++c) acc = fmaf(hh[c], muT[c*128 + t], acc);
    v = acc; oidx = b*128 + t;
  } else {
    const int u = t - 128;
    float acc = bc[3328 + u];
    const float* spT = wh + 49152;
    for (int c = 0; c < 128; ++c) acc = fmaf(hh[c], spT[c*128 + u], acc);
    v = (acc > 20.f) ? acc : log1pf(__expf(acc));
    oidx = 4096 + b*128 + u;
  }
  if (fl) ((bf16*)out)[oidx] = __float2bfloat16(v);
  else    ((float*)out)[oidx] = v;
}

// ---------------------------------------------------------------------------
extern "C" void kernel_launch(void* const* d_in, const int* in_sizes, int n_in,
                              void* d_out, int out_size, void* d_ws, size_t ws_size,
                              hipStream_t stream)
{
  (void)in_sizes; (void)n_in; (void)out_size; (void)ws_size;
  float* ws    = (float*)d_ws;
  float* x     = ws + 16;                          // 524288
  float* kq    = x + 524288;                       // 1048576
  float* Pf    = kq + 1048576;                     // 524288
  unsigned* Qpk = (unsigned*)(Pf + 524288);        // 262144
  float* g     = (float*)(Qpk + 262144);           // 524288
  unsigned short* wfb = (unsigned short*)(g + 524288);   // 524288 shorts
  unsigned short* w3b = wfb + 524288;              // 393216 shorts
  float* wh    = (float*)(w3b + 393216);           // 65536
  float* bc    = wh + 65536;                       // 3456

  prep_kernel<<<dim3(89), dim3(256), 0, stream>>>(
      d_in[0], d_in[1], d_in[2], d_in[3], d_in[5], d_in[9], d_in[11],
      d_in[13], d_in[15], d_in[17],
      d_in[4], d_in[6], d_in[7], d_in[8], d_in[10], d_in[12],
      d_in[14], d_in[16], d_in[18],
      wfb, w3b, wh, bc);
  k1l0<<<dim3(512), dim3(256), 0, stream>>>(d_in[0], wfb, bc, kq, Pf, Qpk);
  k23_attn<<<dim3(1024), dim3(256), 0, stream>>>(kq, Pf, Qpk, g);
  k41_mix_kq<<<dim3(256), dim3(512), 0, stream>>>(g, w3b, wfb, bc, d_in[0], x, kq, Pf, Qpk);
  k23_attn<<<dim3(1024), dim3(256), 0, stream>>>(kq, Pf, Qpk, g);
  k4_fin<<<dim3(256), dim3(512), 0, stream>>>(g, w3b, bc, x);
  k5_head<<<dim3(32), dim3(256), 0, stream>>>(x, wh, bc, d_in[0], (void*)d_out);
}